// Round 7
// baseline (120.882 us; speedup 1.0000x reference)
//
#include <hip/hip_runtime.h>
#include <math.h>

#define NWAVE 8
#define NTYPE 4
#define NSUB  4     // sub-bins per atom (p&3) -> 4x less atomic contention
#define SCAP  64    // slots per sub-bin (fan-in/sub ~Poisson(10); P(>64)~1e-30)
#define CAP   (NSUB * SCAP)   // 256 slots per atom total

// ---------------------------------------------------------------------------
// R7: attack fill's contended atomic (320k RMWs on 8000 cursors = 40-way
// same-address contention; R1 anchor: contended atomics ~19G/s -> ~17us).
// Sub-bin by (p&3): 4x more cursors, 4x less contention. Pipeline unchanged:
// memset(128KB) -> fill_binned -> gather (wave/atom, butterfly reduce).
// R6 lesson: fill's VALU work is NOT the cost (div removal was neutral).
// ---------------------------------------------------------------------------

// Kernel 1: one edge per thread; geometry once; bin by (center atom, p&3).
__global__ void __launch_bounds__(256)
fill_binned_kernel(const float* __restrict__ cart,      // (B*N,3)
                   const int*   __restrict__ species,   // (B*N,)
                   const int*   __restrict__ atom_index,// (2,B,P)
                   const float* __restrict__ shifts,    // (B,P,3)
                   int*         __restrict__ cursors,   // (T*NSUB,) pre-zeroed
                   float4*      __restrict__ payload,   // (T,NSUB,SCAP)
                   int BP, int P, int N)
{
    const int p = blockIdx.x * 256 + threadIdx.x;
    if (p >= P) return;
    const int b = blockIdx.y;
    const int e = b * P + p;
    const int base = b * N;

    const int i0 = atom_index[e] + base;
    const int i1 = atom_index[BP + e] + base;
    const float sx = shifts[3 * e + 0];
    const float sy = shifts[3 * e + 1];
    const float sz = shifts[3 * e + 2];
    const float c0x = cart[3 * i0 + 0], c0y = cart[3 * i0 + 1], c0z = cart[3 * i0 + 2];
    const float c1x = cart[3 * i1 + 0], c1y = cart[3 * i1 + 1], c1z = cart[3 * i1 + 2];
    const int sp = species[i1];

    const float dx = c0x - c1x + sx;
    const float dy = c0y - c1y + sy;
    const float dz = c0z - c1z + sz;

    const int sub = p & (NSUB - 1);
    const int pos = atomicAdd(&cursors[i0 * NSUB + sub], 1);
    if (pos < SCAP)
        payload[(size_t)i0 * CAP + sub * SCAP + pos] =
            make_float4(dx, dy, dz, __int_as_float(sp));
}

// Kernel 2: one wave per atom. lane = slice*8 + m; slices stride each
// sub-bin; butterfly-reduce over slice bits (8,16,32); slice 0 writes out.
__global__ void __launch_bounds__(256)
atom_gather_kernel(const float4* __restrict__ payload,
                   const int4* __restrict__ cursors,  // (T,) int4 = 4 sub-counts
                   const float* __restrict__ rs,      // (4,8)
                   const float* __restrict__ inta,    // (4,8)
                   const float* __restrict__ params,  // (4,24)
                   const float* __restrict__ hyper,   // (3,8,8)
                   float* __restrict__ out, int T)
{
    __shared__ float sh_rs[NTYPE * NWAVE];
    __shared__ float sh_inta[NTYPE * NWAVE];
    int tid = threadIdx.x;
    if (tid < 32) { sh_rs[tid] = rs[tid]; sh_inta[tid] = inta[tid]; }
    __syncthreads();

    int t    = blockIdx.x * 4 + (tid >> 6);
    int lane = tid & 63;
    int s    = lane >> 3;    // edge slice 0..7
    int m    = lane & 7;     // wave channel 0..7
    if (t >= T) return;

    float hcol0[8], hcol1[8], hcol2[8];
#pragma unroll
    for (int k = 0; k < 8; ++k) {
        hcol0[k] = hyper[       k * 8 + m];
        hcol1[k] = hyper[ 64 +  k * 8 + m];
        hcol2[k] = hyper[128 +  k * 8 + m];
    }
    float par[NTYPE][3];
#pragma unroll
    for (int sp = 0; sp < NTYPE; ++sp)
#pragma unroll
        for (int p = 0; p < 3; ++p)
            par[sp][p] = params[sp * 24 + p * 8 + m];

    int4 c4 = cursors[t];
    int cnt[NSUB] = { c4.x, c4.y, c4.z, c4.w };
#pragma unroll
    for (int j = 0; j < NSUB; ++j) if (cnt[j] > SCAP) cnt[j] = SCAP;

    const float4* __restrict__ pl = payload + (size_t)t * CAP;

    float a0 = 0.f;
    float a1x = 0.f, a1y = 0.f, a1z = 0.f;
    float axx = 0.f, ayy = 0.f, azz = 0.f, axy = 0.f, axz = 0.f, ayz = 0.f;

#pragma unroll
    for (int j = 0; j < NSUB; ++j) {
        const float4* __restrict__ plj = pl + j * SCAP;
        for (int i = s; i < cnt[j]; i += 8) {
            float4 d = plj[i];
            int sp = __float_as_int(d.w);
            float dx = d.x, dy = d.y, dz = d.z;
            float dist = sqrtf(dx * dx + dy * dy + dz * dz);
            float inv = 1.0f / dist;
            float ux = dx * inv, uy = dy * inv, uz = dz * inv;
            float fc = 0.5f * __cosf(dist * (float)(M_PI / 5.0)) + 0.5f;
            fc = fc * fc;
            float r0 = 0.f, r1 = 0.f, r2 = 0.f;
#pragma unroll
            for (int k = 0; k < 8; ++k) {
                float dd = dist - sh_rs[sp * 8 + k];
                float rad = __expf(-sh_inta[sp * 8 + k] * dd * dd);
                r0 += rad * hcol0[k];
                r1 += rad * hcol1[k];
                r2 += rad * hcol2[k];
            }
            float W0 = fc * r0 * par[sp][0];
            float W1 = fc * r1 * par[sp][1];
            float W2 = fc * r2 * par[sp][2];
            a0 += W0;
            a1x += ux * W1; a1y += uy * W1; a1z += uz * W1;
            float tx = ux * W2, ty = uy * W2;
            axx += tx * ux; axy += tx * uy; axz += tx * uz;
            ayy += ty * uy; ayz += ty * uz;
            azz += uz * uz * W2;
        }
    }

#define RED(v) v += __shfl_xor(v, 8); v += __shfl_xor(v, 16); v += __shfl_xor(v, 32)
    RED(a0);
    RED(a1x); RED(a1y); RED(a1z);
    RED(axx); RED(ayy); RED(azz); RED(axy); RED(axz); RED(ayz);
#undef RED

    if (s == 0) {
        float o0 = a0 * a0;
        float o1 = a1x * a1x + a1y * a1y + a1z * a1z;
        float o2 = axx * axx + ayy * ayy + azz * azz
                 + 2.0f * (axy * axy + axz * axz + ayz * ayz);
        float* o = out + (size_t)t * 24;
        o[m] = o0; o[8 + m] = o1; o[16 + m] = o2;
    }
}

// ---------------------------------------------------------------------------
extern "C" void kernel_launch(void* const* d_in, const int* in_sizes, int n_in,
                              void* d_out, int out_size, void* d_ws, size_t ws_size,
                              hipStream_t stream)
{
    const float* cart       = (const float*)d_in[0];
    const int*   species    = (const int*)  d_in[2];
    const int*   atom_index = (const int*)  d_in[3];
    const float* shifts     = (const float*)d_in[4];
    const float* rs         = (const float*)d_in[5];
    const float* inta       = (const float*)d_in[6];
    const float* params     = (const float*)d_in[7];
    const float* hyper      = (const float*)d_in[8];

    const int B  = in_sizes[1];          // 8
    const int N  = in_sizes[2] / B;      // 1000
    const int BP = in_sizes[3] / 2;      // 320000
    const int P  = BP / B;               // 40000
    const int T  = B * N;                // 8000

    char* ws = (char*)d_ws;
    float4* payload = (float4*)ws;                       // T*CAP*16 = 32.8 MB
    int*    cursors = (int*)(ws + (size_t)T * CAP * 16); // T*NSUB ints (16B-aligned)

    hipMemsetAsync(cursors, 0, (size_t)T * NSUB * sizeof(int), stream);

    dim3 fgrid((P + 255) / 256, B);
    fill_binned_kernel<<<fgrid, 256, 0, stream>>>(
        cart, species, atom_index, shifts, cursors, payload, BP, P, N);

    atom_gather_kernel<<<(T + 3) / 4, 256, 0, stream>>>(
        payload, (const int4*)cursors, rs, inta, params, hyper, (float*)d_out, T);
}